// Round 4
// baseline (118.009 us; speedup 1.0000x reference)
//
#include <hip/hip_runtime.h>
#include <hip/hip_bf16.h>

#define B_ 8
#define N_ 2048
#define D_ 512
#define DK_ 64

typedef float f32x4 __attribute__((ext_vector_type(4)));
typedef short bf16x8 __attribute__((ext_vector_type(8)));
typedef unsigned short u16;

__device__ __forceinline__ u16 f2bf(float f) {
  union { float f; unsigned u; } v; v.f = f;
  unsigned r = v.u + 0x7FFFu + ((v.u >> 16) & 1u);  // RNE, inputs finite
  return (u16)(r >> 16);
}

#define MFMA16(a, b, cacc) __builtin_amdgcn_mfma_f32_16x16x32_bf16((a), (b), (cacc), 0, 0, 0)

// ---------------------------------------------------------------------------
// Kernel 1: X [B,N,D] f32  ->  XT [B,D,N] bf16   (V operand, kv-contiguous)
// ---------------------------------------------------------------------------
__global__ __launch_bounds__(256) void xt_kernel(const float* __restrict__ X,
                                                 u16* __restrict__ XT) {
  int bid = blockIdx.x;
  int dt = bid & 7, nt = (bid >> 3) & 31, b = bid >> 8;
  int n0 = nt * 64, d0 = dt * 64;
  __shared__ u16 T[64 * 68];
  int t = threadIdx.x;
  const float* Xb = X + ((size_t)b * N_ + n0) * D_ + d0;
#pragma unroll
  for (int p = 0; p < 4; ++p) {
    int r = p * 16 + (t >> 4);
    int c4 = (t & 15) * 4;
    f32x4 v = *reinterpret_cast<const f32x4*>(Xb + (size_t)r * D_ + c4);
#pragma unroll
    for (int j = 0; j < 4; ++j) T[(c4 + j) * 68 + r] = f2bf(v[j]);
  }
  __syncthreads();
  u16* XTb = XT + ((size_t)b * D_ + d0) * N_ + n0;
#pragma unroll
  for (int p = 0; p < 8; ++p) {
    int j = p * 8 + (t >> 5);
    int i = t & 31;
    unsigned v2 = *reinterpret_cast<const unsigned*>(&T[j * 68 + 2 * i]);
    *reinterpret_cast<unsigned*>(XTb + (size_t)j * N_ + 2 * i) = v2;
  }
}

// ---------------------------------------------------------------------------
// Kernel 2: Qbf = (h@WQ + bQ)/8,  Kbf = X@WK + bK   (bf16 out, MFMA)
// ---------------------------------------------------------------------------
__global__ __launch_bounds__(256) void proj_kernel(
    const float* __restrict__ h, const float* __restrict__ X,
    const float* __restrict__ WQ, const float* __restrict__ bQ,
    const float* __restrict__ WK, const float* __restrict__ bK,
    u16* __restrict__ Qbf, u16* __restrict__ Kbf) {
  int bid = blockIdx.x;
  int b = bid & 7, nt = bid >> 3;
  int n0 = nt * 64;
  int t = threadIdx.x, w = t >> 6, l = t & 63, g = l >> 4, c = l & 15;
  int arow = n0 + w * 16 + c;
  const float* hrow = h + ((size_t)b * N_ + arow) * D_;
  const float* Xrow = X + ((size_t)b * N_ + arow) * D_;
  f32x4 accq[4], acck[4];
#pragma unroll
  for (int cf = 0; cf < 4; ++cf) {
    accq[cf] = (f32x4){0.f, 0.f, 0.f, 0.f};
    acck[cf] = (f32x4){0.f, 0.f, 0.f, 0.f};
  }
  for (int k0 = 0; k0 < D_; k0 += 32) {
    bf16x8 ah, ax;
    {
      f32x4 h0 = *reinterpret_cast<const f32x4*>(hrow + k0 + 8 * g);
      f32x4 h1 = *reinterpret_cast<const f32x4*>(hrow + k0 + 8 * g + 4);
      f32x4 x0 = *reinterpret_cast<const f32x4*>(Xrow + k0 + 8 * g);
      f32x4 x1 = *reinterpret_cast<const f32x4*>(Xrow + k0 + 8 * g + 4);
#pragma unroll
      for (int i = 0; i < 4; ++i) {
        ah[i] = (short)f2bf(h0[i]); ah[i + 4] = (short)f2bf(h1[i]);
        ax[i] = (short)f2bf(x0[i]); ax[i + 4] = (short)f2bf(x1[i]);
      }
    }
#pragma unroll
    for (int cf = 0; cf < 4; ++cf) {
      bf16x8 bq, bk;
#pragma unroll
      for (int i = 0; i < 8; ++i) {
        int kk = k0 + 8 * g + i;
        bq[i] = (short)f2bf(WQ[(size_t)kk * DK_ + cf * 16 + c]);
        bk[i] = (short)f2bf(WK[(size_t)kk * DK_ + cf * 16 + c]);
      }
      accq[cf] = MFMA16(ah, bq, accq[cf]);
      acck[cf] = MFMA16(ax, bk, acck[cf]);
    }
  }
#pragma unroll
  for (int cf = 0; cf < 4; ++cf) {
    float vq = bQ[cf * 16 + c], vk = bK[cf * 16 + c];
#pragma unroll
    for (int r = 0; r < 4; ++r) {
      int q = n0 + w * 16 + 4 * g + r;
      Qbf[((size_t)b * N_ + q) * DK_ + cf * 16 + c] = f2bf((accq[cf][r] + vq) * 0.125f);
      Kbf[((size_t)b * N_ + q) * DK_ + cf * 16 + c] = f2bf(acck[cf][r] + vk);
    }
  }
}

// ---------------------------------------------------------------------------
// Kernel 3: fused attention. 256 blocks x 512 threads (8 waves).
// Block = 64 q x 512 d. b = bid&7 (XCD pin -> XT[b] 2MB L2-resident).
// V and K are loaded DIRECTLY from L2 in B-frag layout into registers,
// prefetched one kv-tile ahead (2-deep reg double buffer). Each 64B line is
// fully consumed (4 lanes x 16B), so no LDS staging needed. Only P goes
// through LDS (cross-wave exchange), double-buffered; ONE lgkm-only barrier
// per iter keeps the 10 prefetch loads in flight across it.
// ---------------------------------------------------------------------------
__global__ __launch_bounds__(512, 1) void attn_kernel(
    const u16* __restrict__ Qbf, const u16* __restrict__ Kbf,
    const u16* __restrict__ XT, float* __restrict__ out) {
  int bid = blockIdx.x;
  int b = bid & 7, qt = bid >> 3;
  int q0 = qt * 64;
  int t = threadIdx.x, w = t >> 6, l = t & 63, g = l >> 4, c = l & 15;
  int qh = w >> 2, kq = w & 3;          // S-slab coords

  __shared__ u16 Plds[2][64][72];       // P double buffer [q 64][kv 64]
  __shared__ float Lp[4][64];

  const u16* Qb  = Qbf + (size_t)b * N_ * DK_;
  const u16* Kb  = Kbf + (size_t)b * N_ * DK_;
  const u16* XTw = XT + (size_t)b * D_ * N_ + (size_t)(w * 64) * N_;

  // resident Q A-frags: Q[q0+qh*32+qf*16+c][ks*32+8g..+8]
  bf16x8 aq[2][2];
#pragma unroll
  for (int qf = 0; qf < 2; ++qf)
#pragma unroll
    for (int ks = 0; ks < 2; ++ks)
      aq[qf][ks] = *reinterpret_cast<const bf16x8*>(
          Qb + (size_t)(q0 + qh * 32 + qf * 16 + c) * DK_ + ks * 32 + 8 * g);

  f32x4 o[4][4];
#pragma unroll
  for (int a = 0; a < 4; ++a)
#pragma unroll
    for (int d = 0; d < 4; ++d) o[a][d] = (f32x4){0.f, 0.f, 0.f, 0.f};
  float lp[2][4];
#pragma unroll
  for (int a = 0; a < 2; ++a)
#pragma unroll
    for (int r = 0; r < 4; ++r) lp[a][r] = 0.f;

  // V B-frag addr: XTw[(df*16+c)*N + kv0 + ks*32 + 8g], frag idx = ks*4+df
  // K B-frag addr: Kb[(kv0 + kq*16 + c)*DK + ks*32 + 8g]
  bf16x8 vA[8], vB[8], kA[2], kB[2];

#pragma unroll
  for (int ks = 0; ks < 2; ++ks) {
    kA[ks] = *reinterpret_cast<const bf16x8*>(
        Kb + (size_t)(kq * 16 + c) * DK_ + ks * 32 + 8 * g);
#pragma unroll
    for (int df = 0; df < 4; ++df)
      vA[ks * 4 + df] = *reinterpret_cast<const bf16x8*>(
          XTw + (size_t)(df * 16 + c) * N_ + ks * 32 + 8 * g);
  }

  auto body = [&](bf16x8 (&vC)[8], bf16x8 (&kC)[2],
                  bf16x8 (&vN)[8], bf16x8 (&kN)[2], int i) {
    const int pb = i & 1;
    const int kvn = ((i + 1) & 31) * 64;

    // issue next-tile V/K frag loads (in flight across the barrier)
#pragma unroll
    for (int ks = 0; ks < 2; ++ks) {
      kN[ks] = *reinterpret_cast<const bf16x8*>(
          Kb + (size_t)(kvn + kq * 16 + c) * DK_ + ks * 32 + 8 * g);
#pragma unroll
      for (int df = 0; df < 4; ++df)
        vN[ks * 4 + df] = *reinterpret_cast<const bf16x8*>(
            XTw + (size_t)(df * 16 + c) * N_ + kvn + ks * 32 + 8 * g);
    }

    // ---- S = Q/8 @ K^T for this wave's [32q][16kv] slab (register-only)
    f32x4 s0 = (f32x4){0.f, 0.f, 0.f, 0.f};
    f32x4 s1 = (f32x4){0.f, 0.f, 0.f, 0.f};
    s0 = MFMA16(aq[0][0], kC[0], s0); s0 = MFMA16(aq[0][1], kC[1], s0);
    s1 = MFMA16(aq[1][0], kC[0], s1); s1 = MFMA16(aq[1][1], kC[1], s1);

    // ---- P = exp(S), partial sums, write P slab (bf16)
#pragma unroll
    for (int r = 0; r < 4; ++r) {
      float p0 = __expf(s0[r]); lp[0][r] += p0;
      Plds[pb][qh * 32 + 4 * g + r][kq * 16 + c] = f2bf(p0);
      float p1 = __expf(s1[r]); lp[1][r] += p1;
      Plds[pb][qh * 32 + 16 + 4 * g + r][kq * 16 + c] = f2bf(p1);
    }

    // ---- barrier WITHOUT vmcnt drain: P visible, prefetch stays in flight
    asm volatile("s_waitcnt lgkmcnt(0)" ::: "memory");
    __builtin_amdgcn_s_barrier();
    asm volatile("" ::: "memory");

    // ---- O += P @ V  (P from LDS, V from registers)
#pragma unroll
    for (int ks = 0; ks < 2; ++ks) {
      bf16x8 pa0 = *reinterpret_cast<const bf16x8*>(&Plds[pb][c][ks * 32 + 8 * g]);
      bf16x8 pa1 = *reinterpret_cast<const bf16x8*>(&Plds[pb][16 + c][ks * 32 + 8 * g]);
      bf16x8 pa2 = *reinterpret_cast<const bf16x8*>(&Plds[pb][32 + c][ks * 32 + 8 * g]);
      bf16x8 pa3 = *reinterpret_cast<const bf16x8*>(&Plds[pb][48 + c][ks * 32 + 8 * g]);
#pragma unroll
      for (int df = 0; df < 4; ++df) {
        o[0][df] = MFMA16(pa0, vC[ks * 4 + df], o[0][df]);
        o[1][df] = MFMA16(pa1, vC[ks * 4 + df], o[1][df]);
        o[2][df] = MFMA16(pa2, vC[ks * 4 + df], o[2][df]);
        o[3][df] = MFMA16(pa3, vC[ks * 4 + df], o[3][df]);
      }
    }
  };

#pragma unroll 1
  for (int i = 0; i < 32; i += 2) {
    body(vA, kA, vB, kB, i);
    body(vB, kB, vA, kA, i + 1);
  }

  // ---- denominator: reduce lp over 16 c-lanes, combine across kq waves
#pragma unroll
  for (int qf = 0; qf < 2; ++qf)
#pragma unroll
    for (int r = 0; r < 4; ++r) {
      float v = lp[qf][r];
      v += __shfl_xor(v, 1); v += __shfl_xor(v, 2);
      v += __shfl_xor(v, 4); v += __shfl_xor(v, 8);
      lp[qf][r] = v;
    }
  if (c == 0) {
#pragma unroll
    for (int qf = 0; qf < 2; ++qf)
#pragma unroll
      for (int r = 0; r < 4; ++r)
        Lp[kq][qh * 32 + qf * 16 + 4 * g + r] = lp[qf][r];
  }
  __syncthreads();

  float* outb = out + ((size_t)b * N_ + q0) * D_;
#pragma unroll
  for (int qf2 = 0; qf2 < 4; ++qf2)
#pragma unroll
    for (int r = 0; r < 4; ++r) {
      int ql = qf2 * 16 + 4 * g + r;
      float L = Lp[0][ql] + Lp[1][ql] + Lp[2][ql] + Lp[3][ql];
      float inv = 1.0f / L;
#pragma unroll
      for (int df = 0; df < 4; ++df)
        outb[(size_t)ql * D_ + w * 64 + df * 16 + c] = o[qf2][df][r] * inv;
    }
}

// ---------------------------------------------------------------------------
extern "C" void kernel_launch(void* const* d_in, const int* in_sizes, int n_in,
                              void* d_out, int out_size, void* d_ws, size_t ws_size,
                              hipStream_t stream) {
  const float* X  = (const float*)d_in[0];
  const float* h  = (const float*)d_in[1];
  const float* WQ = (const float*)d_in[2];
  const float* bQ = (const float*)d_in[3];
  const float* WK = (const float*)d_in[4];
  const float* bK = (const float*)d_in[5];
  float* out = (float*)d_out;

  u16* XT  = (u16*)d_ws;                               // 16 MB
  u16* Qbf = XT + (size_t)B_ * D_ * N_;                // 2 MB
  u16* Kbf = Qbf + (size_t)B_ * N_ * DK_;              // 2 MB

  xt_kernel<<<dim3(2048), dim3(256), 0, stream>>>(X, XT);
  proj_kernel<<<dim3(256), dim3(256), 0, stream>>>(h, X, WQ, bQ, WK, bK, Qbf, Kbf);
  attn_kernel<<<dim3(256), dim3(512), 0, stream>>>(Qbf, Kbf, XT, out);
}

// Round 6
// 81.342 us; speedup vs baseline: 1.4508x; 1.4508x over previous
//
#include <hip/hip_runtime.h>
#include <hip/hip_bf16.h>

#define B_ 8
#define N_ 2048
#define D_ 512
#define DK_ 64

typedef float f32x4 __attribute__((ext_vector_type(4)));
typedef short bf16x8 __attribute__((ext_vector_type(8)));
typedef unsigned short u16;

__device__ __forceinline__ u16 f2bf(float f) {
  union { float f; unsigned u; } v; v.f = f;
  unsigned r = v.u + 0x7FFFu + ((v.u >> 16) & 1u);  // RNE, inputs finite
  return (u16)(r >> 16);
}

#define MFMA16(a, b, cacc) __builtin_amdgcn_mfma_f32_16x16x32_bf16((a), (b), (cacc), 0, 0, 0)

// ===========================================================================
// Fragment layouts (every attn global load = 64 lanes x 16B contiguous 1KB):
//  Qf/Kf: elem((b*128 + slab)*2 + ks)*512 + lane*8 + i
//         holds  M[slab*16 + (lane&15)][ks*32 + (lane>>4)*8 + i]
//  Vf:    elem(((b*32 + dt)*32 + kvt)*2 + ks)*512 + lane*8 + i
//         holds  X[kvt*64 + ks*32 + (lane>>4)*8 + i][dt*16 + (lane&15)]
// ===========================================================================

// ---------------------------------------------------------------------------
// Kernel 1 (R1-validated structure, frag-line stores): X f32 -> Vf bf16.
// grid 2048 = b(8) x nt(32) x dt(8); 64x64 tile via LDS transpose.
// ---------------------------------------------------------------------------
__global__ __launch_bounds__(256) void vt_kernel(const float* __restrict__ X,
                                                 u16* __restrict__ Vf) {
  int bid = blockIdx.x;
  int dt = bid & 7, nt = (bid >> 3) & 31, b = bid >> 8;
  int n0 = nt * 64, d0 = dt * 64;
  __shared__ u16 T[64 * 72];  // T[d_local][n_local], stride 72 u16 (144B, 16B-mult)
  int t = threadIdx.x;
  const float* Xb = X + ((size_t)b * N_ + n0) * D_ + d0;
#pragma unroll
  for (int p = 0; p < 4; ++p) {
    int r = p * 16 + (t >> 4);      // n_local
    int c4 = (t & 15) * 4;          // d_local base
    f32x4 v = *reinterpret_cast<const f32x4*>(Xb + (size_t)r * D_ + c4);
#pragma unroll
    for (int j = 0; j < 4; ++j) T[(c4 + j) * 72 + r] = f2bf(v[j]);
  }
  __syncthreads();
  // frag-line stores: wave w -> dt2 = dt*4 + w, lane l, ks = 0..1
  int w = t >> 6, l = t & 63, g = l >> 4, c = l & 15;
#pragma unroll
  for (int ks = 0; ks < 2; ++ks) {
    bf16x8 v = *reinterpret_cast<const bf16x8*>(&T[(w * 16 + c) * 72 + ks * 32 + 8 * g]);
    *reinterpret_cast<bf16x8*>(
        Vf + (((size_t)(b * 32 + dt * 4 + w) * 32 + nt) * 2 + ks) * 512 + l * 8) = v;
  }
}

// ---------------------------------------------------------------------------
// Kernel 2 (R1-validated structure, frag-line stores):
//  Qf = (h@WQ + bQ)/8,  Kf = X@WK + bK.  grid 256 = b(8) x nt(32).
// ---------------------------------------------------------------------------
__global__ __launch_bounds__(256) void proj_kernel(
    const float* __restrict__ h, const float* __restrict__ X,
    const float* __restrict__ WQ, const float* __restrict__ bQ,
    const float* __restrict__ WK, const float* __restrict__ bK,
    u16* __restrict__ Qf, u16* __restrict__ Kf) {
  int bid = blockIdx.x;
  int b = bid & 7, nt = bid >> 3;
  int n0 = nt * 64;
  int t = threadIdx.x, w = t >> 6, l = t & 63, g = l >> 4, c = l & 15;
  int arow = n0 + w * 16 + c;
  const float* hrow = h + ((size_t)b * N_ + arow) * D_;
  const float* Xrow = X + ((size_t)b * N_ + arow) * D_;
  f32x4 accq[4], acck[4];
#pragma unroll
  for (int cf = 0; cf < 4; ++cf) {
    accq[cf] = (f32x4){0.f, 0.f, 0.f, 0.f};
    acck[cf] = (f32x4){0.f, 0.f, 0.f, 0.f};
  }
  for (int k0 = 0; k0 < D_; k0 += 32) {
    bf16x8 ah, ax;
    {
      f32x4 h0 = *reinterpret_cast<const f32x4*>(hrow + k0 + 8 * g);
      f32x4 h1 = *reinterpret_cast<const f32x4*>(hrow + k0 + 8 * g + 4);
      f32x4 x0 = *reinterpret_cast<const f32x4*>(Xrow + k0 + 8 * g);
      f32x4 x1 = *reinterpret_cast<const f32x4*>(Xrow + k0 + 8 * g + 4);
#pragma unroll
      for (int i = 0; i < 4; ++i) {
        ah[i] = (short)f2bf(h0[i]); ah[i + 4] = (short)f2bf(h1[i]);
        ax[i] = (short)f2bf(x0[i]); ax[i + 4] = (short)f2bf(x1[i]);
      }
    }
#pragma unroll
    for (int cf = 0; cf < 4; ++cf) {
      bf16x8 bq, bk;
#pragma unroll
      for (int i = 0; i < 8; ++i) {
        int kk = k0 + 8 * g + i;
        bq[i] = (short)f2bf(WQ[(size_t)kk * DK_ + cf * 16 + c]);
        bk[i] = (short)f2bf(WK[(size_t)kk * DK_ + cf * 16 + c]);
      }
      accq[cf] = MFMA16(ah, bq, accq[cf]);
      acck[cf] = MFMA16(ax, bk, acck[cf]);
    }
  }
  // frag-layout stores: value row q = n0 + w*16 + 4g + r, col dk = cf*16 + c
  // -> slab nt*4 + w, ks = dk>>5, lane = (((dk&31)>>3)<<4) | (4g+r), i = dk&7
#pragma unroll
  for (int cf = 0; cf < 4; ++cf) {
    float vq = bQ[cf * 16 + c], vk = bK[cf * 16 + c];
    int ks = cf >> 1;
    int g2 = ((cf & 1) * 16 + c) >> 3;
    int i2 = c & 7;
#pragma unroll
    for (int r = 0; r < 4; ++r) {
      size_t e = ((size_t)(b * 128 + nt * 4 + w) * 2 + ks) * 512 +
                 (g2 * 16 + 4 * g + r) * 8 + i2;
      Qf[e] = f2bf((accq[cf][r] + vq) * 0.125f);
      Kf[e] = f2bf(acck[cf][r] + vk);
    }
  }
}

// ---------------------------------------------------------------------------
// attn: 256 blocks x 512 threads (8 waves). Block = 64 q x 512 d.
// b = bid&7 (XCD pin). All global loads are contiguous 1KB frag-lines.
// V/K in registers, prefetched 1 tile ahead (issued at body top so S+exp
// hides L2 latency); P through LDS double buffer; ONE __syncthreads per iter
// (full drain -- proven-safe barrier; lgkm-only variant to be A/B'd later).
// ---------------------------------------------------------------------------
__global__ __launch_bounds__(512, 1) void attn_kernel(
    const u16* __restrict__ Qf, const u16* __restrict__ Kf,
    const u16* __restrict__ Vf, float* __restrict__ out) {
  int bid = blockIdx.x;
  int b = bid & 7, qt = bid >> 3;
  int q0 = qt * 64;
  int t = threadIdx.x, w = t >> 6, l = t & 63, g = l >> 4, c = l & 15;
  int qh = w >> 2, kq = w & 3;          // S-slab coords

  __shared__ u16 Plds[2][64][72];       // P double buffer [q 64][kv 64]
  __shared__ float Lp[4][64];

  // resident Q A-frags: slab = qt*4 + qh*2 + qf
  bf16x8 aq[2][2];
#pragma unroll
  for (int qf = 0; qf < 2; ++qf)
#pragma unroll
    for (int ks = 0; ks < 2; ++ks)
      aq[qf][ks] = *reinterpret_cast<const bf16x8*>(
          Qf + ((size_t)(b * 128 + qt * 4 + qh * 2 + qf) * 2 + ks) * 512 + l * 8);

  f32x4 o[4][4];
#pragma unroll
  for (int a = 0; a < 4; ++a)
#pragma unroll
    for (int d = 0; d < 4; ++d) o[a][d] = (f32x4){0.f, 0.f, 0.f, 0.f};
  float lp[2][4];
#pragma unroll
  for (int a = 0; a < 2; ++a)
#pragma unroll
    for (int r = 0; r < 4; ++r) lp[a][r] = 0.f;

  // frag-line bases (u16 elems)
  const u16* Kbase = Kf + (size_t)(b * 128 + kq) * 2 * 512 + l * 8;   // slab = kvt*4+kq
  const u16* Vbase = Vf + ((size_t)(b * 32 + w * 4) * 32) * 2 * 512 + l * 8;

  bf16x8 vA[8], vB[8], kA[2], kB[2];
#pragma unroll
  for (int ks = 0; ks < 2; ++ks) {
    kA[ks] = *reinterpret_cast<const bf16x8*>(Kbase + (size_t)ks * 512);
#pragma unroll
    for (int df = 0; df < 4; ++df)
      vA[ks * 4 + df] = *reinterpret_cast<const bf16x8*>(
          Vbase + ((size_t)df * 32 * 2 + ks) * 512);
  }

  auto body = [&](bf16x8 (&vC)[8], bf16x8 (&kC)[2],
                  bf16x8 (&vN)[8], bf16x8 (&kN)[2], int i) {
    const int pb = i & 1;
    const int kvn = (i + 1) & 31;

    // issue next-tile V/K frag loads early (contiguous 1KB each)
#pragma unroll
    for (int ks = 0; ks < 2; ++ks) {
      kN[ks] = *reinterpret_cast<const bf16x8*>(
          Kbase + ((size_t)kvn * 4 * 2 + ks) * 512);
#pragma unroll
      for (int df = 0; df < 4; ++df)
        vN[ks * 4 + df] = *reinterpret_cast<const bf16x8*>(
            Vbase + (((size_t)df * 32 + kvn) * 2 + ks) * 512);
    }

    // ---- S = Q/8 @ K^T for this wave's [32q][16kv] slab (register-only)
    f32x4 s0 = (f32x4){0.f, 0.f, 0.f, 0.f};
    f32x4 s1 = (f32x4){0.f, 0.f, 0.f, 0.f};
    s0 = MFMA16(aq[0][0], kC[0], s0); s0 = MFMA16(aq[0][1], kC[1], s0);
    s1 = MFMA16(aq[1][0], kC[0], s1); s1 = MFMA16(aq[1][1], kC[1], s1);

    // ---- P = exp(S), partial sums, write P slab (bf16)
#pragma unroll
    for (int r = 0; r < 4; ++r) {
      float p0 = __expf(s0[r]); lp[0][r] += p0;
      Plds[pb][qh * 32 + 4 * g + r][kq * 16 + c] = f2bf(p0);
      float p1 = __expf(s1[r]); lp[1][r] += p1;
      Plds[pb][qh * 32 + 16 + 4 * g + r][kq * 16 + c] = f2bf(p1);
    }

    // ---- single full barrier per iter (safe: P dbuf windowed-hazard-free)
    __syncthreads();

    // ---- O += P @ V  (P from LDS, V from registers)
#pragma unroll
    for (int ks = 0; ks < 2; ++ks) {
      bf16x8 pa0 = *reinterpret_cast<const bf16x8*>(&Plds[pb][c][ks * 32 + 8 * g]);
      bf16x8 pa1 = *reinterpret_cast<const bf16x8*>(&Plds[pb][16 + c][ks * 32 + 8 * g]);
      bf16x8 pa2 = *reinterpret_cast<const bf16x8*>(&Plds[pb][32 + c][ks * 32 + 8 * g]);
      bf16x8 pa3 = *reinterpret_cast<const bf16x8*>(&Plds[pb][48 + c][ks * 32 + 8 * g]);
#pragma unroll
      for (int df = 0; df < 4; ++df) {
        o[0][df] = MFMA16(pa0, vC[ks * 4 + df], o[0][df]);
        o[1][df] = MFMA16(pa1, vC[ks * 4 + df], o[1][df]);
        o[2][df] = MFMA16(pa2, vC[ks * 4 + df], o[2][df]);
        o[3][df] = MFMA16(pa3, vC[ks * 4 + df], o[3][df]);
      }
    }
  };

#pragma unroll 1
  for (int i = 0; i < 32; i += 2) {
    body(vA, kA, vB, kB, i);
    body(vB, kB, vA, kA, i + 1);
  }

  // ---- denominator: reduce lp over 16 c-lanes, combine across kq waves
#pragma unroll
  for (int qf = 0; qf < 2; ++qf)
#pragma unroll
    for (int r = 0; r < 4; ++r) {
      float v = lp[qf][r];
      v += __shfl_xor(v, 1); v += __shfl_xor(v, 2);
      v += __shfl_xor(v, 4); v += __shfl_xor(v, 8);
      lp[qf][r] = v;
    }
  if (c == 0) {
#pragma unroll
    for (int qf = 0; qf < 2; ++qf)
#pragma unroll
      for (int r = 0; r < 4; ++r)
        Lp[kq][qh * 32 + qf * 16 + 4 * g + r] = lp[qf][r];
  }
  __syncthreads();

  float* outb = out + ((size_t)b * N_ + q0) * D_;
#pragma unroll
  for (int qf2 = 0; qf2 < 4; ++qf2)
#pragma unroll
    for (int r = 0; r < 4; ++r) {
      int ql = qf2 * 16 + 4 * g + r;
      float L = Lp[0][ql] + Lp[1][ql] + Lp[2][ql] + Lp[3][ql];
      float inv = 1.0f / L;
#pragma unroll
      for (int df = 0; df < 4; ++df)
        outb[(size_t)ql * D_ + w * 64 + df * 16 + c] = o[qf2][df][r] * inv;
    }
}

// ---------------------------------------------------------------------------
extern "C" void kernel_launch(void* const* d_in, const int* in_sizes, int n_in,
                              void* d_out, int out_size, void* d_ws, size_t ws_size,
                              hipStream_t stream) {
  const float* X  = (const float*)d_in[0];
  const float* h  = (const float*)d_in[1];
  const float* WQ = (const float*)d_in[2];
  const float* bQ = (const float*)d_in[3];
  const float* WK = (const float*)d_in[4];
  const float* bK = (const float*)d_in[5];
  float* out = (float*)d_out;

  u16* Vf = (u16*)d_ws;                                // 16 MB
  u16* Qf = Vf + (size_t)B_ * D_ * N_;                 // 2 MB
  u16* Kf = Qf + (size_t)B_ * N_ * DK_;                // 2 MB

  vt_kernel<<<dim3(2048), dim3(256), 0, stream>>>(X, Vf);
  proj_kernel<<<dim3(256), dim3(256), 0, stream>>>(h, X, WQ, bQ, WK, bK, Qf, Kf);
  attn_kernel<<<dim3(256), dim3(512), 0, stream>>>(Qf, Kf, Vf, out);
}

// Round 7
// 81.226 us; speedup vs baseline: 1.4529x; 1.0014x over previous
//
#include <hip/hip_runtime.h>
#include <hip/hip_bf16.h>

#define B_ 8
#define N_ 2048
#define D_ 512
#define DK_ 64

typedef float f32x4 __attribute__((ext_vector_type(4)));
typedef short bf16x8 __attribute__((ext_vector_type(8)));
typedef unsigned short u16;

__device__ __forceinline__ u16 f2bf(float f) {
  union { float f; unsigned u; } v; v.f = f;
  unsigned r = v.u + 0x7FFFu + ((v.u >> 16) & 1u);  // RNE, inputs finite
  return (u16)(r >> 16);
}

#define MFMA16(a, b, cacc) __builtin_amdgcn_mfma_f32_16x16x32_bf16((a), (b), (cacc), 0, 0, 0)

// ===========================================================================
// Fragment layouts (every attn global load = 64 lanes x 16B contiguous 1KB):
//  Qf/Kf: elem((b*128 + slab)*2 + ks)*512 + lane*8 + i
//         holds  M[slab*16 + (lane&15)][ks*32 + (lane>>4)*8 + i]
//  Vf:    elem(((b*32 + dt)*32 + kvt)*2 + ks)*512 + lane*8 + i
//         holds  X[kvt*64 + ks*32 + (lane>>4)*8 + i][dt*16 + (lane&15)]
// ===========================================================================

// ---------------------------------------------------------------------------
// Kernel 1 (validated): X f32 -> Vf bf16 frag layout.
// ---------------------------------------------------------------------------
__global__ __launch_bounds__(256) void vt_kernel(const float* __restrict__ X,
                                                 u16* __restrict__ Vf) {
  int bid = blockIdx.x;
  int dt = bid & 7, nt = (bid >> 3) & 31, b = bid >> 8;
  int n0 = nt * 64, d0 = dt * 64;
  __shared__ u16 T[64 * 72];  // T[d_local][n_local]
  int t = threadIdx.x;
  const float* Xb = X + ((size_t)b * N_ + n0) * D_ + d0;
#pragma unroll
  for (int p = 0; p < 4; ++p) {
    int r = p * 16 + (t >> 4);      // n_local
    int c4 = (t & 15) * 4;          // d_local base
    f32x4 v = *reinterpret_cast<const f32x4*>(Xb + (size_t)r * D_ + c4);
#pragma unroll
    for (int j = 0; j < 4; ++j) T[(c4 + j) * 72 + r] = f2bf(v[j]);
  }
  __syncthreads();
  int w = t >> 6, l = t & 63, g = l >> 4, c = l & 15;
#pragma unroll
  for (int ks = 0; ks < 2; ++ks) {
    bf16x8 v = *reinterpret_cast<const bf16x8*>(&T[(w * 16 + c) * 72 + ks * 32 + 8 * g]);
    *reinterpret_cast<bf16x8*>(
        Vf + (((size_t)(b * 32 + dt * 4 + w) * 32 + nt) * 2 + ks) * 512 + l * 8) = v;
  }
}

// ---------------------------------------------------------------------------
// Kernel 2 (validated): Qf = (h@WQ + bQ)/8, Kf = X@WK + bK, frag layout.
// ---------------------------------------------------------------------------
__global__ __launch_bounds__(256) void proj_kernel(
    const float* __restrict__ h, const float* __restrict__ X,
    const float* __restrict__ WQ, const float* __restrict__ bQ,
    const float* __restrict__ WK, const float* __restrict__ bK,
    u16* __restrict__ Qf, u16* __restrict__ Kf) {
  int bid = blockIdx.x;
  int b = bid & 7, nt = bid >> 3;
  int n0 = nt * 64;
  int t = threadIdx.x, w = t >> 6, l = t & 63, g = l >> 4, c = l & 15;
  int arow = n0 + w * 16 + c;
  const float* hrow = h + ((size_t)b * N_ + arow) * D_;
  const float* Xrow = X + ((size_t)b * N_ + arow) * D_;
  f32x4 accq[4], acck[4];
#pragma unroll
  for (int cf = 0; cf < 4; ++cf) {
    accq[cf] = (f32x4){0.f, 0.f, 0.f, 0.f};
    acck[cf] = (f32x4){0.f, 0.f, 0.f, 0.f};
  }
  for (int k0 = 0; k0 < D_; k0 += 32) {
    bf16x8 ah, ax;
    {
      f32x4 h0 = *reinterpret_cast<const f32x4*>(hrow + k0 + 8 * g);
      f32x4 h1 = *reinterpret_cast<const f32x4*>(hrow + k0 + 8 * g + 4);
      f32x4 x0 = *reinterpret_cast<const f32x4*>(Xrow + k0 + 8 * g);
      f32x4 x1 = *reinterpret_cast<const f32x4*>(Xrow + k0 + 8 * g + 4);
#pragma unroll
      for (int i = 0; i < 4; ++i) {
        ah[i] = (short)f2bf(h0[i]); ah[i + 4] = (short)f2bf(h1[i]);
        ax[i] = (short)f2bf(x0[i]); ax[i + 4] = (short)f2bf(x1[i]);
      }
    }
#pragma unroll
    for (int cf = 0; cf < 4; ++cf) {
      bf16x8 bq, bk;
#pragma unroll
      for (int i = 0; i < 8; ++i) {
        int kk = k0 + 8 * g + i;
        bq[i] = (short)f2bf(WQ[(size_t)kk * DK_ + cf * 16 + c]);
        bk[i] = (short)f2bf(WK[(size_t)kk * DK_ + cf * 16 + c]);
      }
      accq[cf] = MFMA16(ah, bq, accq[cf]);
      acck[cf] = MFMA16(ax, bk, acck[cf]);
    }
  }
#pragma unroll
  for (int cf = 0; cf < 4; ++cf) {
    float vq = bQ[cf * 16 + c], vk = bK[cf * 16 + c];
    int ks = cf >> 1;
    int g2 = ((cf & 1) * 16 + c) >> 3;
    int i2 = c & 7;
#pragma unroll
    for (int r = 0; r < 4; ++r) {
      size_t e = ((size_t)(b * 128 + nt * 4 + w) * 2 + ks) * 512 +
                 (g2 * 16 + 4 * g + r) * 8 + i2;
      Qf[e] = f2bf((accq[cf][r] + vq) * 0.125f);
      Kf[e] = f2bf(acck[cf][r] + vk);
    }
  }
}

// ---------------------------------------------------------------------------
// attn: 256 blocks x 512 threads (8 waves). Block = 64 q x 512 d.
// Schedule change vs R6: prefetch ISSUE moved to just after the barrier
// (loads outstanding at a barrier are now a full iteration old -> the
// vmcnt(0) drain inside __syncthreads is ~free), and s_setprio(1) wraps
// the PV MFMA cluster (T5). Sync structure unchanged (proven full barrier).
// ---------------------------------------------------------------------------
__global__ __launch_bounds__(512, 1) void attn_kernel(
    const u16* __restrict__ Qf, const u16* __restrict__ Kf,
    const u16* __restrict__ Vf, float* __restrict__ out) {
  int bid = blockIdx.x;
  int b = bid & 7, qt = bid >> 3;
  int q0 = qt * 64;
  int t = threadIdx.x, w = t >> 6, l = t & 63, g = l >> 4, c = l & 15;
  int qh = w >> 2, kq = w & 3;          // S-slab coords

  __shared__ u16 Plds[2][64][72];       // P double buffer [q 64][kv 64]
  __shared__ float Lp[4][64];

  // resident Q A-frags: slab = qt*4 + qh*2 + qf
  bf16x8 aq[2][2];
#pragma unroll
  for (int qf = 0; qf < 2; ++qf)
#pragma unroll
    for (int ks = 0; ks < 2; ++ks)
      aq[qf][ks] = *reinterpret_cast<const bf16x8*>(
          Qf + ((size_t)(b * 128 + qt * 4 + qh * 2 + qf) * 2 + ks) * 512 + l * 8);

  f32x4 o[4][4];
#pragma unroll
  for (int a = 0; a < 4; ++a)
#pragma unroll
    for (int d = 0; d < 4; ++d) o[a][d] = (f32x4){0.f, 0.f, 0.f, 0.f};
  float lp[2][4];
#pragma unroll
  for (int a = 0; a < 2; ++a)
#pragma unroll
    for (int r = 0; r < 4; ++r) lp[a][r] = 0.f;

  // frag-line bases (u16 elems)
  const u16* Kbase = Kf + (size_t)(b * 128 + kq) * 2 * 512 + l * 8;   // slab = kvt*4+kq
  const u16* Vbase = Vf + ((size_t)(b * 32 + w * 4) * 32) * 2 * 512 + l * 8;

  bf16x8 vA[8], vB[8], kA[2], kB[2];
#pragma unroll
  for (int ks = 0; ks < 2; ++ks) {
    kA[ks] = *reinterpret_cast<const bf16x8*>(Kbase + (size_t)ks * 512);
#pragma unroll
    for (int df = 0; df < 4; ++df)
      vA[ks * 4 + df] = *reinterpret_cast<const bf16x8*>(
          Vbase + ((size_t)df * 32 * 2 + ks) * 512);
  }

  auto body = [&](bf16x8 (&vC)[8], bf16x8 (&kC)[2],
                  bf16x8 (&vN)[8], bf16x8 (&kN)[2], int i) {
    const int pb = i & 1;
    const int kvn = (i + 1) & 31;

    // ---- S = Q/8 @ K^T for this wave's [32q][16kv] slab (register-only)
    f32x4 s0 = (f32x4){0.f, 0.f, 0.f, 0.f};
    f32x4 s1 = (f32x4){0.f, 0.f, 0.f, 0.f};
    s0 = MFMA16(aq[0][0], kC[0], s0); s0 = MFMA16(aq[0][1], kC[1], s0);
    s1 = MFMA16(aq[1][0], kC[0], s1); s1 = MFMA16(aq[1][1], kC[1], s1);

    // ---- P = exp(S), partial sums, write P slab (bf16)
#pragma unroll
    for (int r = 0; r < 4; ++r) {
      float p0 = __expf(s0[r]); lp[0][r] += p0;
      Plds[pb][qh * 32 + 4 * g + r][kq * 16 + c] = f2bf(p0);
      float p1 = __expf(s1[r]); lp[1][r] += p1;
      Plds[pb][qh * 32 + 16 + 4 * g + r][kq * 16 + c] = f2bf(p1);
    }

    // ---- single full barrier per iter; outstanding vmem here is one full
    // iteration old (issued at previous iter's post-barrier point) -> cheap.
    __syncthreads();

    // ---- issue next-tile K/V frag loads NOW (K first: consumed first).
    // First use of kN = next iter's S (one PV phase away); vN = next PV.
#pragma unroll
    for (int ks = 0; ks < 2; ++ks)
      kN[ks] = *reinterpret_cast<const bf16x8*>(
          Kbase + ((size_t)kvn * 4 * 2 + ks) * 512);
#pragma unroll
    for (int ks = 0; ks < 2; ++ks)
#pragma unroll
      for (int df = 0; df < 4; ++df)
        vN[ks * 4 + df] = *reinterpret_cast<const bf16x8*>(
            Vbase + (((size_t)df * 32 + kvn) * 2 + ks) * 512);

    // ---- O += P @ V  (P from LDS, V from registers), prioritized
    bf16x8 pa0, pa1, pa2, pa3;
    __builtin_amdgcn_s_setprio(1);
#pragma unroll
    for (int ks = 0; ks < 2; ++ks) {
      pa0 = *reinterpret_cast<const bf16x8*>(&Plds[pb][c][ks * 32 + 8 * g]);
      pa1 = *reinterpret_cast<const bf16x8*>(&Plds[pb][16 + c][ks * 32 + 8 * g]);
      pa2 = *reinterpret_cast<const bf16x8*>(&Plds[pb][32 + c][ks * 32 + 8 * g]);
      pa3 = *reinterpret_cast<const bf16x8*>(&Plds[pb][48 + c][ks * 32 + 8 * g]);
#pragma unroll
      for (int df = 0; df < 4; ++df) {
        o[0][df] = MFMA16(pa0, vC[ks * 4 + df], o[0][df]);
        o[1][df] = MFMA16(pa1, vC[ks * 4 + df], o[1][df]);
        o[2][df] = MFMA16(pa2, vC[ks * 4 + df], o[2][df]);
        o[3][df] = MFMA16(pa3, vC[ks * 4 + df], o[3][df]);
      }
    }
    __builtin_amdgcn_s_setprio(0);
  };

#pragma unroll 1
  for (int i = 0; i < 32; i += 2) {
    body(vA, kA, vB, kB, i);
    body(vB, kB, vA, kA, i + 1);
  }

  // ---- denominator: reduce lp over 16 c-lanes, combine across kq waves
#pragma unroll
  for (int qf = 0; qf < 2; ++qf)
#pragma unroll
    for (int r = 0; r < 4; ++r) {
      float v = lp[qf][r];
      v += __shfl_xor(v, 1); v += __shfl_xor(v, 2);
      v += __shfl_xor(v, 4); v += __shfl_xor(v, 8);
      lp[qf][r] = v;
    }
  if (c == 0) {
#pragma unroll
    for (int qf = 0; qf < 2; ++qf)
#pragma unroll
      for (int r = 0; r < 4; ++r)
        Lp[kq][qh * 32 + qf * 16 + 4 * g + r] = lp[qf][r];
  }
  __syncthreads();

  float* outb = out + ((size_t)b * N_ + q0) * D_;
#pragma unroll
  for (int qf2 = 0; qf2 < 4; ++qf2)
#pragma unroll
    for (int r = 0; r < 4; ++r) {
      int ql = qf2 * 16 + 4 * g + r;
      float L = Lp[0][ql] + Lp[1][ql] + Lp[2][ql] + Lp[3][ql];
      float inv = 1.0f / L;
#pragma unroll
      for (int df = 0; df < 4; ++df)
        outb[(size_t)ql * D_ + w * 64 + df * 16 + c] = o[qf2][df][r] * inv;
    }
}

// ---------------------------------------------------------------------------
extern "C" void kernel_launch(void* const* d_in, const int* in_sizes, int n_in,
                              void* d_out, int out_size, void* d_ws, size_t ws_size,
                              hipStream_t stream) {
  const float* X  = (const float*)d_in[0];
  const float* h  = (const float*)d_in[1];
  const float* WQ = (const float*)d_in[2];
  const float* bQ = (const float*)d_in[3];
  const float* WK = (const float*)d_in[4];
  const float* bK = (const float*)d_in[5];
  float* out = (float*)d_out;

  u16* Vf = (u16*)d_ws;                                // 16 MB
  u16* Qf = Vf + (size_t)B_ * D_ * N_;                 // 2 MB
  u16* Kf = Qf + (size_t)B_ * N_ * DK_;                // 2 MB

  vt_kernel<<<dim3(2048), dim3(256), 0, stream>>>(X, Vf);
  proj_kernel<<<dim3(256), dim3(256), 0, stream>>>(h, X, WQ, bQ, WK, bK, Qf, Kf);
  attn_kernel<<<dim3(256), dim3(512), 0, stream>>>(Qf, Kf, Vf, out);
}